// Round 12
// baseline (196.553 us; speedup 1.0000x reference)
//
#include <hip/hip_runtime.h>
#include <hip/hip_fp16.h>

// NCC loss, v8: two-pass, centered-fp16 intermediates.
// Pass1 redesign: 32x64 tile (1.41x halo), field-planar LDS sw[5][72][36]
// (stride 36 = 4 mod 32 banks -> <=2-way), stage B = 128 jobs of w-run4 x
// h-run4: 60 ds_read_b128 per 16 outputs + dwordx2 fp16 stores (1.25/out).
// Pass2 (R10-proven): per-column D-stream with register ring, no LDS/barriers.
#define ND 2
#define DD 160
#define HH 192
#define WW 160
#define HW (HH * WW)
#define DHW (DD * HH * WW)
#define VOX (ND * DHW)          // 9,830,400 voxels per field

__device__ __forceinline__ void slide4(const float x[12], float S[4]) {
    float f = ((x[0] + x[1]) + (x[2] + x[3]))
            + ((x[4] + x[5]) + (x[6] + x[7])) + x[8];
    S[0] = f;
    f += x[9]  - x[0]; S[1] = f;
    f += x[10] - x[1]; S[2] = f;
    f += x[11] - x[2]; S[3] = f;
}

// ---------------------------------------------------------------------------
// Pass 1: per (n,d) slice, 32(w) x 64(h) output tile.
// ---------------------------------------------------------------------------
constexpr int P1TW = 32;
constexpr int P1TH = 64;
constexpr int P1RH = P1TH + 8;   // 72 W-sum rows incl. H halo
constexpr int P1CP = 36;         // padded cols (32 used): 36 % 32 = 4 -> skew

__global__ __launch_bounds__(256)
void ncc_pass1(const float* __restrict__ I, const float* __restrict__ J,
               __half* __restrict__ ws)
{
    __shared__ float sw[5][P1RH][P1CP];   // 51.8 KB, field-planar W-sums

    const int tid = threadIdx.x;
    const int w0  = blockIdx.x * P1TW;    // 0,32,...,128
    const int h0  = blockIdx.y * P1TH;    // 0,64,128
    const int z   = blockIdx.z;           // n*DD + d
    const int sbase = z * HW;

    // ---- stage A: 576 jobs = 72 rows x 8 groups of 4 W-sum outputs ----
    for (int idx = tid; idx < P1RH * 8; idx += 256) {
        const int r  = idx >> 3;          // 0..71
        const int g  = idx & 7;           // 0..7
        const int gh = h0 + r - 4;
        const bool hok = (gh >= 0) && (gh < HH);
        const int rbase = sbase + gh * WW;
        const int ws0 = w0 + g * 4 - 4;

        float a[12], b[12];
        #pragma unroll
        for (int c = 0; c < 3; ++c) {
            const int gw = ws0 + 4 * c;
            float4 va = make_float4(0.f, 0.f, 0.f, 0.f), vb = va;
            if (hok && gw >= 0 && gw < WW) {
                va = *(const float4*)(I + rbase + gw);
                vb = *(const float4*)(J + rbase + gw);
                va.x -= 0.5f; va.y -= 0.5f; va.z -= 0.5f; va.w -= 0.5f;
                vb.x -= 0.5f; vb.y -= 0.5f; vb.z -= 0.5f; vb.w -= 0.5f;
            }
            *(float4*)&a[4 * c] = va;
            *(float4*)&b[4 * c] = vb;
        }
        float S[4], f[12];
        slide4(a, S);
        *(float4*)&sw[0][r][g * 4] = *(float4*)S;
        slide4(b, S);
        *(float4*)&sw[1][r][g * 4] = *(float4*)S;
        #pragma unroll
        for (int i = 0; i < 12; ++i) f[i] = a[i] * a[i];
        slide4(f, S);
        *(float4*)&sw[2][r][g * 4] = *(float4*)S;
        #pragma unroll
        for (int i = 0; i < 12; ++i) f[i] = b[i] * b[i];
        slide4(f, S);
        *(float4*)&sw[3][r][g * 4] = *(float4*)S;
        #pragma unroll
        for (int i = 0; i < 12; ++i) f[i] = a[i] * b[i];
        slide4(f, S);
        *(float4*)&sw[4][r][g * 4] = *(float4*)S;
    }
    __syncthreads();

    // ---- stage B: 128 jobs = 8 w-groups(4 wide) x 16 h-groups(4 high) ----
    if (tid < 128) {
        const int gw  = tid & 7;          // w-group
        const int gh4 = tid >> 3;         // h-group, 0..15
        const int rb  = gh4 * 4;          // first tap row
        const int wc  = w0 + gw * 4;      // output w base
        const int hb  = h0 + gh4 * 4;     // output h base

        #pragma unroll
        for (int p = 0; p < 5; ++p) {
            float4 f[12];
            #pragma unroll
            for (int q = 0; q < 12; ++q)
                f[q] = *(const float4*)&sw[p][rb + q][gw * 4];

            float4 t[4];
            t[0].x = ((f[0].x + f[1].x) + (f[2].x + f[3].x))
                   + ((f[4].x + f[5].x) + (f[6].x + f[7].x)) + f[8].x;
            t[0].y = ((f[0].y + f[1].y) + (f[2].y + f[3].y))
                   + ((f[4].y + f[5].y) + (f[6].y + f[7].y)) + f[8].y;
            t[0].z = ((f[0].z + f[1].z) + (f[2].z + f[3].z))
                   + ((f[4].z + f[5].z) + (f[6].z + f[7].z)) + f[8].z;
            t[0].w = ((f[0].w + f[1].w) + (f[2].w + f[3].w))
                   + ((f[4].w + f[5].w) + (f[6].w + f[7].w)) + f[8].w;
            #pragma unroll
            for (int k = 1; k < 4; ++k) {
                t[k].x = t[k-1].x + f[k+8].x - f[k-1].x;
                t[k].y = t[k-1].y + f[k+8].y - f[k-1].y;
                t[k].z = t[k-1].z + f[k+8].z - f[k-1].z;
                t[k].w = t[k-1].w + f[k+8].w - f[k-1].w;
            }
            __half* wp = ws + (size_t)p * VOX + sbase + wc;
            #pragma unroll
            for (int k = 0; k < 4; ++k) {
                union { __half h[4]; uint2 u; } pk;
                pk.h[0] = __float2half(t[k].x);
                pk.h[1] = __float2half(t[k].y);
                pk.h[2] = __float2half(t[k].z);
                pk.h[3] = __float2half(t[k].w);
                *(uint2*)(wp + (hb + k) * WW) = pk.u;
            }
        }
    }
}

// ---------------------------------------------------------------------------
// Pass 2: per (n,h,w) column, stream D with a 9-slot register ring. No LDS,
// no barriers. Reconstruct uncentered sums via cnt, cc, atomic reduce.
// ---------------------------------------------------------------------------
constexpr int P2CH = 40;
constexpr int P2NS = P2CH + 8;

__global__ __launch_bounds__(256)
void ncc_pass2(const __half* __restrict__ ws, float* __restrict__ outp)
{
    const int col = blockIdx.x * 256 + threadIdx.x;   // 0..61439
    const int d0  = blockIdx.y * P2CH;
    const int n   = col / HW;
    const int rem = col - n * HW;
    const int h   = rem / WW;
    const int w   = rem - h * WW;
    const int base = n * DHW + rem;

    const float cW = (float)(min(w + 4, WW - 1) - max(w - 4, 0) + 1);
    const float cH = (float)(min(h + 4, HH - 1) - max(h - 4, 0) + 1);
    const float cHW = cW * cH;

    float ring[5][9];
    #pragma unroll
    for (int p = 0; p < 5; ++p)
        #pragma unroll
        for (int q = 0; q < 9; ++q) ring[p][q] = 0.f;
    float run0 = 0.f, run1 = 0.f, run2 = 0.f, run3 = 0.f, run4 = 0.f;
    float acc = 0.f;
    const float inv = 1.0f / 729.0f;

    #pragma unroll 1
    for (int g = 0; g < 6; ++g) {
        #pragma unroll
        for (int jj = 0; jj < 9; ++jj) {
            const int s = g * 9 + jj;
            if (s < P2NS) {
                const int dd = d0 - 4 + s;
                float v0 = 0.f, v1 = 0.f, v2 = 0.f, v3 = 0.f, v4 = 0.f;
                if (dd >= 0 && dd < DD) {
                    const int a = base + dd * HW;
                    v0 = __half2float(ws[0 * VOX + a]);
                    v1 = __half2float(ws[1 * VOX + a]);
                    v2 = __half2float(ws[2 * VOX + a]);
                    v3 = __half2float(ws[3 * VOX + a]);
                    v4 = __half2float(ws[4 * VOX + a]);
                }
                run0 += v0 - ring[0][jj]; ring[0][jj] = v0;
                run1 += v1 - ring[1][jj]; ring[1][jj] = v1;
                run2 += v2 - ring[2][jj]; ring[2][jj] = v2;
                run3 += v3 - ring[3][jj]; ring[3][jj] = v3;
                run4 += v4 - ring[4][jj]; ring[4][jj] = v4;

                if (s >= 8) {
                    const int d = d0 + s - 8;
                    const float cD  = (float)(min(d + 4, DD - 1) - max(d - 4, 0) + 1);
                    const float cnt = cHW * cD;
                    const float Is  = run0 + 0.5f * cnt;
                    const float Js  = run1 + 0.5f * cnt;
                    const float I2  = run2 + run0 + 0.25f * cnt;
                    const float J2  = run3 + run1 + 0.25f * cnt;
                    const float IJ  = run4 + 0.5f * (run0 + run1) + 0.25f * cnt;
                    const float uI = Is * inv, uJ = Js * inv;
                    const float cross = IJ - uI * Js;
                    const float Iv = fmaxf(I2 - uI * Is, 1e-5f);
                    const float Jv = fmaxf(J2 - uJ * Js, 1e-5f);
                    acc += cross * cross / (Iv * Jv + 1e-5f);
                }
            }
        }
    }

    __shared__ float wred[4];
    #pragma unroll
    for (int off = 32; off > 0; off >>= 1)
        acc += __shfl_down(acc, off, 64);
    const int lane = threadIdx.x & 63, wid = threadIdx.x >> 6;
    if (lane == 0) wred[wid] = acc;
    __syncthreads();
    if (threadIdx.x == 0)
        atomicAdd(outp, -(wred[0] + wred[1] + wred[2] + wred[3]));
}

// ---------------------------------------------------------------------------
// Fallback (ws too small): R9's fused kernel, known-passing at ~134 us.
// ---------------------------------------------------------------------------
constexpr int FTW = 16, FTH = 16, FHLO = FTH + 8;
constexpr int FCH = 20, FNCH = DD / FCH, FNSL = FCH + 8, FNR = FNSL / 2;

__global__ __launch_bounds__(256, 4)
void ncc_fused(const float* __restrict__ I, const float* __restrict__ J,
               float* __restrict__ outp)
{
    __shared__ float4 sws[2][FHLO][FTW + 1];
    __shared__ float  sw4[2][FHLO][FTW + 1];
    __shared__ float  wred[4];

    const int tid = threadIdx.x;
    const int w0 = blockIdx.x * FTW, h0 = blockIdx.y * FTH;
    const int z = blockIdx.z, n = z / FNCH, d0 = (z % FNCH) * FCH;
    const int lane = tid & 63, wid = tid >> 6;
    const int oh = tid >> 4, ow = tid & 15;
    const bool ajob = (tid < 192);
    const int sl = tid / 96, rj = tid - sl * 96;
    const int arow = rj >> 2, awg = rj & 3;
    const int agh = h0 + arow - 4, agws = w0 + awg * 4 - 4;
    const bool ahok = (agh >= 0) && (agh < HH);

    float rbuf[5][9];
    #pragma unroll
    for (int p = 0; p < 5; ++p)
        #pragma unroll
        for (int q = 0; q < 9; ++q) rbuf[p][q] = 0.f;
    float run0 = 0.f, run1 = 0.f, run2 = 0.f, run3 = 0.f, run4 = 0.f;
    float acc = 0.f;
    const float inv = 1.0f / 729.0f;

    #pragma unroll 1
    for (int g = 0; g < 2; ++g) {
        #pragma unroll
        for (int r = 0; r < 9; ++r) {
            const int rr = g * 9 + r;
            if (rr < FNR) {
                const int s0 = 2 * rr, dd0 = d0 - 4 + s0;
                if (ajob) {
                    const int dd = dd0 + sl;
                    if (dd >= 0 && dd < DD) {
                        float a[12], b[12];
                        const int rbase = (n * DD + dd) * HW + agh * WW;
                        #pragma unroll
                        for (int c = 0; c < 3; ++c) {
                            const int gw = agws + 4 * c;
                            float4 va = make_float4(0.f, 0.f, 0.f, 0.f), vb = va;
                            if (ahok && gw >= 0 && gw < WW) {
                                va = *(const float4*)(I + rbase + gw);
                                vb = *(const float4*)(J + rbase + gw);
                            }
                            *(float4*)&a[4 * c] = va;
                            *(float4*)&b[4 * c] = vb;
                        }
                        float S0[4], S1[4], S2[4], S3[4], S4[4], f[12];
                        slide4(a, S0);
                        slide4(b, S1);
                        #pragma unroll
                        for (int i = 0; i < 12; ++i) f[i] = a[i] * a[i];
                        slide4(f, S2);
                        #pragma unroll
                        for (int i = 0; i < 12; ++i) f[i] = b[i] * b[i];
                        slide4(f, S3);
                        #pragma unroll
                        for (int i = 0; i < 12; ++i) f[i] = a[i] * b[i];
                        slide4(f, S4);
                        #pragma unroll
                        for (int t = 0; t < 4; ++t) {
                            sws[sl][arow][awg * 4 + t] =
                                make_float4(S0[t], S1[t], S2[t], S3[t]);
                            sw4[sl][arow][awg * 4 + t] = S4[t];
                        }
                    }
                }
                __syncthreads();
                #pragma unroll
                for (int half = 0; half < 2; ++half) {
                    const int ddx = dd0 + half, sx = s0 + half;
                    float t0 = 0.f, t1 = 0.f, t2 = 0.f, t3 = 0.f, t4 = 0.f;
                    if (ddx >= 0 && ddx < DD) {
                        #pragma unroll
                        for (int q = 0; q < 9; ++q) {
                            const float4 v = sws[half][oh + q][ow];
                            t0 += v.x; t1 += v.y; t2 += v.z; t3 += v.w;
                            t4 += sw4[half][oh + q][ow];
                        }
                    }
                    const int jj = (2 * r + half) % 9;
                    run0 += t0 - rbuf[0][jj]; rbuf[0][jj] = t0;
                    run1 += t1 - rbuf[1][jj]; rbuf[1][jj] = t1;
                    run2 += t2 - rbuf[2][jj]; rbuf[2][jj] = t2;
                    run3 += t3 - rbuf[3][jj]; rbuf[3][jj] = t3;
                    run4 += t4 - rbuf[4][jj]; rbuf[4][jj] = t4;
                    if (sx >= 8) {
                        const float uI = run0 * inv, uJ = run1 * inv;
                        const float cross = run4 - uI * run1;
                        const float Iv = fmaxf(run2 - uI * run0, 1e-5f);
                        const float Jv = fmaxf(run3 - uJ * run1, 1e-5f);
                        acc += cross * cross / (Iv * Jv + 1e-5f);
                    }
                }
                __syncthreads();
            }
        }
    }
    #pragma unroll
    for (int off = 32; off > 0; off >>= 1)
        acc += __shfl_down(acc, off, 64);
    if (lane == 0) wred[wid] = acc;
    __syncthreads();
    if (tid == 0)
        atomicAdd(outp, -(wred[0] + wred[1] + wred[2] + wred[3]));
}

extern "C" void kernel_launch(void* const* d_in, const int* in_sizes, int n_in,
                              void* d_out, int out_size, void* d_ws, size_t ws_size,
                              hipStream_t stream)
{
    const float* I = (const float*)d_in[0];   // y_true
    const float* J = (const float*)d_in[1];   // y_pred
    float* out = (float*)d_out;

    hipMemsetAsync(out, 0, sizeof(float), stream);

    const size_t need = (size_t)5 * VOX * sizeof(__half);   // 98.3 MB
    if (ws_size >= need) {
        __half* ws = (__half*)d_ws;
        dim3 g1(WW / P1TW, HH / P1TH, ND * DD);   // 5 x 3 x 320 = 4800
        ncc_pass1<<<g1, 256, 0, stream>>>(I, J, ws);
        dim3 g2(ND * HW / 256, DD / P2CH);        // 240 x 4 = 960
        ncc_pass2<<<g2, 256, 0, stream>>>(ws, out);
    } else {
        dim3 grid(WW / FTW, HH / FTH, ND * FNCH); // 10 x 12 x 16
        ncc_fused<<<grid, 256, 0, stream>>>(I, J, out);
    }
}